// Round 6
// baseline (244.377 us; speedup 1.0000x reference)
//
#include <hip/hip_runtime.h>

#define NB 32
#define NP 512
#define NS 1024
#define NH 1024
#define NR 256
#define K3 3072

#define BM 64

typedef _Float16 half8 __attribute__((ext_vector_type(8)));
typedef float f32x4 __attribute__((ext_vector_type(4)));

__device__ __forceinline__ f32x4 mfma_f16(half8 a, half8 b, f32x4 c) {
  return __builtin_amdgcn_mfma_f32_16x16x32_f16(a, b, c, 0, 0, 0);
}

// Raw workgroup barrier without the vmem drain (R5; neutral but correct --
// cross-wave deps are LDS-only, covered by lgkmcnt(0); global loads are
// consumed by the issuing thread under compiler-counted vmcnt waits).
__device__ __forceinline__ void wg_barrier() {
  asm volatile("s_waitcnt lgkmcnt(0)" ::: "memory");
  __builtin_amdgcn_s_barrier();
}

// W fp32 [256][3072] -> FRAGMENT-MAJOR fp16 in ws:
//   WbF[kc][n16][lane] (half8), kc = k3/32 (96), n16 = n/16 (16), lane = lr+16*lg.
//   A wave's B-fragment load is one contiguous 1 KB burst. fp16 (2^-11) beats
//   the old bf16 (2^-9) rounding -- absmax should drop.
__global__ void wconv_kernel(const float* __restrict__ W,
                             _Float16* __restrict__ WbF) {
  int i = blockIdx.x * blockDim.x + threadIdx.x;   // half8 id, 98304 total
  int lane = i & 63, n16 = (i >> 6) & 15, kc = i >> 10;
  int lr = lane & 15, lg = lane >> 4;
  const float* src = W + (size_t)(n16 * 16 + lr) * K3 + kc * 32 + lg * 8;
  float4 a = *(const float4*)src;
  float4 b = *(const float4*)(src + 4);
  half8 o;
  o[0] = (_Float16)a.x; o[1] = (_Float16)a.y;
  o[2] = (_Float16)a.z; o[3] = (_Float16)a.w;
  o[4] = (_Float16)b.x; o[5] = (_Float16)b.y;
  o[6] = (_Float16)b.z; o[7] = (_Float16)b.w;
  *(half8*)(WbF + (size_t)i * 8) = o;
}

// hs fp32 [32,1024,1024] -> fp16/2 (the 0.5 head/tail factor folded in, exact).
// 128 MB read + 64 MB write, dense streaming, ~30 us. This HALVES the gather
// bytes in gemm_kernel -- the R0-R5 invariant 80 us is gather-byte-throughput
// bound (~3.2 TB/s from L3; per-XCD working set 16 MB >> 4 MB L2), so bytes
// are the only lever left.
__global__ void hconv_kernel(const float* __restrict__ hs,
                             _Float16* __restrict__ hsH) {
  size_t i = ((size_t)blockIdx.x * blockDim.x + threadIdx.x) * 8;
  float4 a = *(const float4*)(hs + i);
  float4 b = *(const float4*)(hs + i + 4);
  half8 o;
  o[0] = (_Float16)(0.5f * a.x); o[1] = (_Float16)(0.5f * a.y);
  o[2] = (_Float16)(0.5f * a.z); o[3] = (_Float16)(0.5f * a.w);
  o[4] = (_Float16)(0.5f * b.x); o[5] = (_Float16)(0.5f * b.y);
  o[6] = (_Float16)(0.5f * b.z); o[7] = (_Float16)(0.5f * b.w);
  *(half8*)(hsH + i) = o;
}

// Fused gather + 3-part fp16 MFMA GEMM (R5 schedule, fp16 data path).
// Gather: 1 x 16-B load per source row per thread per stage (4 total, was 8
// fp32 loads): per instr, 8 random rows x 128 B contiguous. h = a'+b' where
// a'=x/2 from hconv (so h is exact-sum of halves); t likewise; p = h*t in
// fp32, rounded once to fp16 (2^-11). MFMA accumulates fp32.
__global__ __launch_bounds__(512, 2) void gemm_kernel(
    const int* __restrict__ pairs, const _Float16* __restrict__ hsH,
    const _Float16* __restrict__ WbF, const float* __restrict__ bias,
    float* __restrict__ out) {
  __shared__ __align__(16) _Float16 sA[2][3][BM][64];  // 49152 B

  const int tid = threadIdx.x;
  const int blk = blockIdx.x;
  // XCD swizzle: blockIdx round-robins over 8 XCDs; give XCD x batches
  // 4x..4x+3 so a batch's 8 M-tiles share one XCD's L2.
  const int x     = blk & 7;
  const int jb    = blk >> 3;
  const int batch = x * 4 + (jb >> 3);
  const int mtile = jb & 7;
  const int m0    = (batch * 8 + mtile) * BM;

  // gather: 8 threads per pair; thread q covers cols 8q..8q+7 (one half8
  // per source row per stage)
  const int pairi = tid >> 3;          // 0..63
  const int q     = tid & 7;
  int4 pr = ((const int4*)pairs)[m0 + pairi];
  const _Float16* hb = hsH + (size_t)batch * NS * NH + 8 * q;
  const _Float16* rp[4];
  rp[0] = hb + (size_t)pr.x * NH;   // h_start
  rp[1] = hb + (size_t)pr.y * NH;   // h_end
  rp[2] = hb + (size_t)pr.z * NH;   // t_start
  rp[3] = hb + (size_t)pr.w * NH;   // t_end

  // MFMA lane mapping: 8 waves, wave w owns N-cols w*32..w*32+31
  const int lane = tid & 63;
  const int w    = tid >> 6;
  const int lr   = lane & 15;
  const int lg   = lane >> 4;

  // frag-major W: half addr = kc*8192 + n16*512 + lane*8; this wave: n16=2w+j
  const _Float16* wbase = WbF + (size_t)(w * 2) * 512 + (size_t)lane * 8;

  f32x4 acc[4][2];
#pragma unroll
  for (int i = 0; i < 4; ++i)
#pragma unroll
    for (int j = 0; j < 2; ++j) acc[i][j] = (f32x4){0.f, 0.f, 0.f, 0.f};

  // gather prefetch, two stages deep (ping-pong); ld[r] = row r's half8.
  half8 ldA[4], ldB[4];
  half8 wcur[12], wnxt[12];     // W frags: idx = part*4 + ks*2 + j

  auto load_w = [&](int s, half8* wd) {
#pragma unroll
    for (int part = 0; part < 3; ++part)
#pragma unroll
      for (int ks = 0; ks < 2; ++ks)
#pragma unroll
        for (int j = 0; j < 2; ++j)
          wd[part * 4 + ks * 2 + j] = *(const half8*)(
              wbase + (size_t)(part * 32 + s * 2 + ks) * 8192 + (size_t)j * 512);
  };

  auto load_gather = [&](int s, half8* ld) {
    const int o = s * 64;
#pragma unroll
    for (int r = 0; r < 4; ++r)
      ld[r] = *(const half8*)(rp[r] + o);
  };

  auto store_stage = [&](int buf, const half8* ld) {
    half8 hv, tv, pv;
#pragma unroll
    for (int e = 0; e < 8; ++e) {
      float h = (float)ld[0][e] + (float)ld[1][e];   // inputs pre-scaled by 0.5
      float t = (float)ld[2][e] + (float)ld[3][e];
      float p = h * t;                 // product in fp32, rounded once
      hv[e] = (_Float16)h; tv[e] = (_Float16)t; pv[e] = (_Float16)p;
    }
    const int col = (q ^ (pairi & 7)) * 8;   // XOR swizzle, all 8 chunks/instr
    *(half8*)&sA[buf][0][pairi][col] = hv;
    *(half8*)&sA[buf][1][pairi][col] = tv;
    *(half8*)&sA[buf][2][pairi][col] = pv;
  };

  auto compute = [&](int buf, half8* wc) {
#pragma unroll
    for (int ks = 0; ks < 2; ++ks) {
      half8 ah[4], at4[4], ap[4];
      const int col = (((ks * 4 + lg) ^ (lr & 7)) * 8);            // XOR swizzle
#pragma unroll
      for (int i = 0; i < 4; ++i) {
        ah[i]  = *(const half8*)&sA[buf][0][i * 16 + lr][col];
        at4[i] = *(const half8*)&sA[buf][1][i * 16 + lr][col];
        ap[i]  = *(const half8*)&sA[buf][2][i * 16 + lr][col];
      }
#pragma unroll
      for (int j = 0; j < 2; ++j)
#pragma unroll
        for (int i = 0; i < 4; ++i) {
          acc[i][j] = mfma_f16(ah[i],  wc[0 + ks * 2 + j], acc[i][j]);
          acc[i][j] = mfma_f16(at4[i], wc[4 + ks * 2 + j], acc[i][j]);
          acc[i][j] = mfma_f16(ap[i],  wc[8 + ks * 2 + j], acc[i][j]);
        }
    }
  };

  // prologue: W(0) -> wcur; g(0) -> ldA; g(1) -> ldB; stage-0 tile to LDS.
  load_w(0, wcur);
  load_gather(0, ldA);
  load_gather(1, ldB);
  store_stage(0, ldA);

  // stage s: barrier (lgkm only); issue W(s+1) then g(s+2) [into the slot
  // consumed at stage s-1]; compute(s); store g(s+1) into buf[s&1^1].
  auto stage = [&](int s, half8* wc, half8* wn, half8* gin, half8* gout) {
    wg_barrier();
    if (s < 15) load_w(s + 1, wn);
    if (s < 14) load_gather(s + 2, gin);
    compute(s & 1, wc);
    if (s < 15) store_stage((s & 1) ^ 1, gout);
  };

#pragma unroll 1
  for (int sp = 0; sp < 8; ++sp) {     // W ping-pong; gather slot parity = s&1
    stage(2 * sp,     wcur, wnxt, ldA, ldB);
    stage(2 * sp + 1, wnxt, wcur, ldB, ldA);
  }

  // Epilogue: C/D layout row=(lane>>4)*4+reg, col=lane&15
#pragma unroll
  for (int j = 0; j < 2; ++j) {
    const int col  = w * 32 + j * 16 + lr;
    const float bv = bias[col];
#pragma unroll
    for (int i = 0; i < 4; ++i) {
      const size_t rbase = (size_t)(m0 + i * 16 + lg * 4) * NR + col;
#pragma unroll
      for (int r = 0; r < 4; ++r)
        out[rbase + (size_t)r * NR] = acc[i][j][r] + bv;
    }
  }
}

extern "C" void kernel_launch(void* const* d_in, const int* in_sizes, int n_in,
                              void* d_out, int out_size, void* d_ws, size_t ws_size,
                              hipStream_t stream) {
  const int*   pairs = (const int*)d_in[0];
  const float* hs    = (const float*)d_in[1];
  const float* W     = (const float*)d_in[2];
  const float* bias  = (const float*)d_in[3];
  float* out = (float*)d_out;
  _Float16* WbF = (_Float16*)d_ws;                         // 1.5 MB fp16 W frags
  _Float16* hsH = (_Float16*)((char*)d_ws + (2u << 20));   // 64 MB fp16 hs/2

  wconv_kernel<<<(96 * 16 * 64) / 256, 256, 0, stream>>>(W, WbF);
  hconv_kernel<<<(NB * NS * NH / 8) / 256, 256, 0, stream>>>(hs, hsH);
  gemm_kernel<<<(NB * NP) / BM, 512, 0, stream>>>(pairs, hsH, WbF, bias, out);
}